// Round 1
// baseline (917.422 us; speedup 1.0000x reference)
//
#include <hip/hip_runtime.h>
#include <math.h>

#define NB 4
#define NH 16
#define NCC 64
#define CSC 64
#define DC 64
#define LP 68          // padded LDS row stride (floats): 16B-aligned rows, conflict-breaking
#define EPSF 1e-6f

__device__ __forceinline__ float red4(float v) {
    v += __shfl_xor(v, 1);
    v += __shfl_xor(v, 2);
    return v;
}

__device__ __forceinline__ void load16(float* dst, const float* src) {
    const float4* p = (const float4*)src;
    float4 a = p[0], b = p[1], c = p[2], d = p[3];
    dst[0]=a.x;  dst[1]=a.y;  dst[2]=a.z;  dst[3]=a.w;
    dst[4]=b.x;  dst[5]=b.y;  dst[6]=b.z;  dst[7]=b.w;
    dst[8]=c.x;  dst[9]=c.y;  dst[10]=c.z; dst[11]=c.w;
    dst[12]=d.x; dst[13]=d.y; dst[14]=d.z; dst[15]=d.w;
}

__device__ __forceinline__ void fma16(float a, const float* w, float* acc) {
#pragma unroll
    for (int i = 0; i < 16; ++i) acc[i] = fmaf(a, w[i], acc[i]);
}

__global__ __launch_bounds__(256, 1) void ttt_kernel(
    const float* __restrict__ xk, const float* __restrict__ xv,
    const float* __restrict__ weight, const float* __restrict__ bias,
    const float* __restrict__ gamma, const float* __restrict__ beta,
    const float* __restrict__ theta, const float* __restrict__ theta_bias,
    const float* __restrict__ alpha, float* __restrict__ out)
{
    __shared__ float Ws[DC][LP];
    __shared__ float xs[CSC][LP];
    __shared__ float gs[CSC][LP];
    __shared__ float bs[DC];

    const int t  = threadIdx.x;
    const int bh = blockIdx.x;            // 0..63  (b*H + h)
    const int h  = bh & (NH - 1);
    const int r  = t >> 2;                // row 0..63
    const int q  = t & 3;                 // col group 0..3
    const int c0 = q * 16;

    // ---- init W, b into LDS ----
    const float* wg = weight + h * DC * DC;
#pragma unroll
    for (int i = 0; i < 4; ++i) {
        int f = t + i * 256;              // float4 index 0..1023
        int d = f >> 4, j = f & 15;
        float4 v = ((const float4*)wg)[f];
        *(float4*)&Ws[d][j * 4] = v;
    }
    if (t < DC) bs[t] = bias[h * DC + t];

    // ---- per-thread constants ----
    float gam[16], bet[16], th[16];
#pragma unroll
    for (int i = 0; i < 16; ++i) {
        gam[i] = gamma[h * DC + c0 + i];
        bet[i] = beta [h * DC + c0 + i];
        th[i]  = theta[h * DC + c0 + i];
    }
    const float tb  = theta_bias[h];
    const float tok = fmaxf(1.0f / (float)(r + 1) + alpha[r], 0.0f);

    const size_t bh_off = (size_t)bh * NCC * CSC * DC;
    const float* xkb = xk + bh_off;
    const float* xvb = xv + bh_off;
    float*       ob  = out + bh_off;

    for (int c = 0; c < NCC; ++c) {
        const float* xkc = xkb + c * CSC * DC;
        const float* xvc = xvb + c * CSC * DC;

        // issue global loads before the barrier (latency overlap)
        float4 xl[4];
#pragma unroll
        for (int i = 0; i < 4; ++i) xl[i] = ((const float4*)xkc)[t + i * 256];
        float xvr[16];
        load16(xvr, xvc + r * DC + c0);

        __syncthreads();                  // prev iteration readers of xs done
#pragma unroll
        for (int i = 0; i < 4; ++i) {
            int f = t + i * 256;
            int d = f >> 4, j = f & 15;
            *(float4*)&xs[d][j * 4] = xl[i];
        }
        __syncthreads();                  // xs visible

        float xkr[16];
        load16(xkr, &xs[r][c0]);

        // lr = sigmoid(xk_row . theta + tb); eta = tok * lr / D
        float p = 0.f;
#pragma unroll
        for (int i = 0; i < 16; ++i) p = fmaf(xkr[i], th[i], p);
        p = red4(p);
        const float lr  = 1.0f / (1.0f + expf(-(p + tb)));
        const float eta = tok * (lr * (1.0f / DC));

        // z = xs @ W + b   (each thread: 16 output cols of its row)
        float acc[16];
#pragma unroll
        for (int i = 0; i < 16; ++i) acc[i] = 0.f;
        for (int d0 = 0; d0 < DC; d0 += 4) {
            float4 a4 = *(const float4*)&xs[r][d0];
            float wv[16];
            load16(wv, &Ws[d0    ][c0]); fma16(a4.x, wv, acc);
            load16(wv, &Ws[d0 + 1][c0]); fma16(a4.y, wv, acc);
            load16(wv, &Ws[d0 + 2][c0]); fma16(a4.z, wv, acc);
            load16(wv, &Ws[d0 + 3][c0]); fma16(a4.w, wv, acc);
        }
        float bv[16];
        load16(bv, &bs[c0]);
#pragma unroll
        for (int i = 0; i < 16; ++i) acc[i] += bv[i];

        // layernorm over D (4-lane reductions)
        float s = 0.f;
#pragma unroll
        for (int i = 0; i < 16; ++i) s += acc[i];
        s = red4(s);
        const float mu = s * (1.0f / DC);
        float vs = 0.f;
#pragma unroll
        for (int i = 0; i < 16; ++i) { float dd = acc[i] - mu; vs = fmaf(dd, dd, vs); }
        vs = red4(vs);
        const float rstd = 1.0f / sqrtf(vs * (1.0f / DC) + EPSF);

        float xh[16], gxh[16];
        float s1 = 0.f, s2 = 0.f;
#pragma unroll
        for (int i = 0; i < 16; ++i) {
            xh[i] = (acc[i] - mu) * rstd;
            float y  = fmaf(gam[i], xh[i], bet[i]);
            float go = y - (xvr[i] - xkr[i]);
            gxh[i] = go * gam[i];
            s1 += gxh[i];
            s2 = fmaf(gxh[i], xh[i], s2);
        }
        s1 = red4(s1);
        s2 = red4(s2);

        // gs[k][e] = eta * grad_x  (feeds both dW and db)
        const float sc = rstd * (1.0f / DC) * eta;
#pragma unroll
        for (int j = 0; j < 4; ++j) {
            float4 v;
            v.x = (64.0f * gxh[4*j  ] - s1 - xh[4*j  ] * s2) * sc;
            v.y = (64.0f * gxh[4*j+1] - s1 - xh[4*j+1] * s2) * sc;
            v.z = (64.0f * gxh[4*j+2] - s1 - xh[4*j+2] * s2) * sc;
            v.w = (64.0f * gxh[4*j+3] - s1 - xh[4*j+3] * s2) * sc;
            *(float4*)&gs[r][c0 + 4 * j] = v;
        }
        __syncthreads();                  // gs ready; all matmul1 reads of W/b done

        // W -= xs^T @ gs  (thread owns W[r][c0..c0+15])
        float dw[16];
#pragma unroll
        for (int i = 0; i < 16; ++i) dw[i] = 0.f;
        for (int k = 0; k < CSC; ++k) {
            float a = xs[k][r];
            float gv[16];
            load16(gv, &gs[k][c0]);
            fma16(a, gv, dw);
        }
#pragma unroll
        for (int j = 0; j < 4; ++j) {
            float4 u = *(float4*)&Ws[r][c0 + 4 * j];
            u.x -= dw[4*j]; u.y -= dw[4*j+1]; u.z -= dw[4*j+2]; u.w -= dw[4*j+3];
            *(float4*)&Ws[r][c0 + 4 * j] = u;
        }
        if (t < DC) {
            float sdb = 0.f;
            for (int k = 0; k < CSC; ++k) sdb += gs[k][t];
            bs[t] -= sdb;
        }
        __syncthreads();                  // W, b updated

        // out = xs @ Wn + bn
#pragma unroll
        for (int i = 0; i < 16; ++i) acc[i] = 0.f;
        for (int d0 = 0; d0 < DC; d0 += 4) {
            float4 a4 = *(const float4*)&xs[r][d0];
            float wv[16];
            load16(wv, &Ws[d0    ][c0]); fma16(a4.x, wv, acc);
            load16(wv, &Ws[d0 + 1][c0]); fma16(a4.y, wv, acc);
            load16(wv, &Ws[d0 + 2][c0]); fma16(a4.z, wv, acc);
            load16(wv, &Ws[d0 + 3][c0]); fma16(a4.w, wv, acc);
        }
        load16(bv, &bs[c0]);
        float* oc = ob + c * CSC * DC + r * DC + c0;
#pragma unroll
        for (int j = 0; j < 4; ++j) {
            float4 v;
            v.x = acc[4*j  ] + bv[4*j  ];
            v.y = acc[4*j+1] + bv[4*j+1];
            v.z = acc[4*j+2] + bv[4*j+2];
            v.w = acc[4*j+3] + bv[4*j+3];
            ((float4*)oc)[j] = v;
        }
    }
}

extern "C" void kernel_launch(void* const* d_in, const int* in_sizes, int n_in,
                              void* d_out, int out_size, void* d_ws, size_t ws_size,
                              hipStream_t stream) {
    const float* xk         = (const float*)d_in[0];
    const float* xv         = (const float*)d_in[1];
    const float* weight     = (const float*)d_in[2];
    const float* bias       = (const float*)d_in[3];
    const float* gamma      = (const float*)d_in[4];
    const float* beta       = (const float*)d_in[5];
    const float* theta      = (const float*)d_in[6];
    const float* theta_bias = (const float*)d_in[7];
    const float* alpha      = (const float*)d_in[8];
    float* out = (float*)d_out;

    ttt_kernel<<<NB * NH, 256, 0, stream>>>(xk, xv, weight, bias, gamma, beta,
                                            theta, theta_bias, alpha, out);
}

// Round 2
// 230.145 us; speedup vs baseline: 3.9863x; 3.9863x over previous
//
#include <hip/hip_runtime.h>
#include <math.h>

#define NB 4
#define NH 16
#define NCC 64
#define CSC 64
#define DC 64
#define S 72            // LDS row stride in bf16 elems (144 B: 16B-aligned, odd multiple of 16 -> 2-way banks only)
#define EPSF 1e-6f

typedef __attribute__((ext_vector_type(8))) short bf16x8;   // 8 bf16 = 4 VGPR (MFMA A/B frag)
typedef __attribute__((ext_vector_type(4))) float f32x4;    // MFMA C/D frag
typedef __attribute__((ext_vector_type(4))) short short4v;

__device__ __forceinline__ short cvt_bf16(float x) {        // RNE f32->bf16
    union { float f; unsigned u; } v; v.f = x;
    unsigned r = v.u + 0x7fffu + ((v.u >> 16) & 1u);
    return (short)(r >> 16);
}
__device__ __forceinline__ float bf16_to_f(short s) {
    union { unsigned u; float f; } v; v.u = ((unsigned)(unsigned short)s) << 16;
    return v.f;
}
__device__ __forceinline__ float red16(float v) {           // sum over 16-lane group
    v += __shfl_xor(v, 1); v += __shfl_xor(v, 2);
    v += __shfl_xor(v, 4); v += __shfl_xor(v, 8);
    return v;
}

__global__ __launch_bounds__(256, 1) void ttt_kernel(
    const float* __restrict__ xk, const float* __restrict__ xv,
    const float* __restrict__ weight, const float* __restrict__ bias,
    const float* __restrict__ gamma, const float* __restrict__ beta,
    const float* __restrict__ theta, const float* __restrict__ theta_bias,
    const float* __restrict__ alpha, float* __restrict__ out)
{
    __shared__ short xs_rm[CSC][S];   // xk chunk, row-major (A of z/out)
    __shared__ short xsT [DC][S];     // xk chunk, transposed (B of dW)
    __shared__ short gsT [DC][S];     // eta*grad_x, transposed (A of dW)
    __shared__ short Wtb [DC][S];     // W^T in bf16 (B of z/out)
    __shared__ float dbp [4][DC];     // per-wave db partials

    const int t  = threadIdx.x;
    const int w  = t >> 6;            // wave 0..3
    const int l  = t & 63;
    const int g  = l >> 4;            // 16-lane group 0..3
    const int la = l & 15;
    const int bh = blockIdx.x;        // 0..63
    const int h  = bh & (NH - 1);

    // per-col constants: cols e_n = 16n + la
    float gam[4], bet[4], thv[4], bcol[4];
#pragma unroll
    for (int n = 0; n < 4; ++n) {
        gam[n]  = gamma[h * DC + 16 * n + la];
        bet[n]  = beta [h * DC + 16 * n + la];
        thv[n]  = theta[h * DC + 16 * n + la];
        bcol[n] = bias [h * DC + 16 * n + la];
    }
    const float tb = theta_bias[h];
    // per-row constants: rows r_i = 16w + 4g + i
    float tok[4];
#pragma unroll
    for (int i = 0; i < 4; ++i) {
        int r = 16 * w + 4 * g + i;
        tok[i] = fmaxf(1.0f / (float)(r + 1) + alpha[r], 0.0f);
    }

    // ---- W state in registers: Wreg[i][n] = W^T[16w+4g+i][16n+la] = W[16n+la][16w+4g+i]
    float Wreg[4][4];
    const float* wg = weight + h * DC * DC;
#pragma unroll
    for (int n = 0; n < 4; ++n)
#pragma unroll
        for (int i = 0; i < 4; ++i)
            Wreg[i][n] = wg[(16 * n + la) * DC + 16 * w + 4 * g + i];
#pragma unroll
    for (int i = 0; i < 4; ++i)
#pragma unroll
        for (int n = 0; n < 4; ++n)
            Wtb[16 * w + 4 * g + i][16 * n + la] = cvt_bf16(Wreg[i][n]);
    __syncthreads();

    // B-frags of W^T (kept across loop: out(c) and z(c+1) share W)
    bf16x8 bw[4][2];
#pragma unroll
    for (int n = 0; n < 4; ++n)
#pragma unroll
        for (int s = 0; s < 2; ++s)
            bw[n][s] = *(const bf16x8*)&Wtb[16 * n + la][8 * g + 32 * s];

    const size_t bh_off = (size_t)bh * NCC * CSC * DC;
    const float* xkb = xk + bh_off;
    const float* xvb = xv + bh_off;
    float*       ob  = out + bh_off;

    // prefetch chunk 0
    float4 xl[4];
#pragma unroll
    for (int i = 0; i < 4; ++i) xl[i] = ((const float4*)xkb)[t + 256 * i];

    for (int c = 0; c < NCC; ++c) {
        // ---- 1. stage xs (row-major + transposed) from prefetched regs
#pragma unroll
        for (int i = 0; i < 4; ++i) {
            int f = t + 256 * i;
            int k = f >> 4, j = f & 15;
            short4v s4;
            s4[0] = cvt_bf16(xl[i].x); s4[1] = cvt_bf16(xl[i].y);
            s4[2] = cvt_bf16(xl[i].z); s4[3] = cvt_bf16(xl[i].w);
            *(short4v*)&xs_rm[k][4 * j] = s4;
            xsT[4 * j + 0][k] = s4[0]; xsT[4 * j + 1][k] = s4[1];
            xsT[4 * j + 2][k] = s4[2]; xsT[4 * j + 3][k] = s4[3];
        }
        // xv in C-layout (fp32, global)
        const float* xvc = xvb + c * CSC * DC;
        float xvf[4][4];
#pragma unroll
        for (int i = 0; i < 4; ++i)
#pragma unroll
            for (int n = 0; n < 4; ++n)
                xvf[i][n] = xvc[(16 * w + 4 * g + i) * DC + 16 * n + la];
        __syncthreads();

        // ---- 2. z = xs @ W   (A row-band 16w.., B = bw regs)
        bf16x8 a0 = *(const bf16x8*)&xs_rm[16 * w + la][8 * g];
        bf16x8 a1 = *(const bf16x8*)&xs_rm[16 * w + la][8 * g + 32];
        f32x4 zacc[4];
#pragma unroll
        for (int n = 0; n < 4; ++n) {
            f32x4 zz = {0.f, 0.f, 0.f, 0.f};
            zz = __builtin_amdgcn_mfma_f32_16x16x32_bf16(a0, bw[n][0], zz, 0, 0, 0);
            zz = __builtin_amdgcn_mfma_f32_16x16x32_bf16(a1, bw[n][1], zz, 0, 0, 0);
            zacc[n] = zz;
        }

        // prefetch next chunk's xk (hides HBM latency under epilogue)
        if (c + 1 < NCC) {
            const float* xkn = xkb + (c + 1) * CSC * DC;
#pragma unroll
            for (int i = 0; i < 4; ++i) xl[i] = ((const float4*)xkn)[t + 256 * i];
        }

        // ---- 3. epilogue (fp32): layernorm + gradient, gs = eta*grad_x
        float xkcf[4][4];
#pragma unroll
        for (int i = 0; i < 4; ++i)
#pragma unroll
            for (int n = 0; n < 4; ++n)
                xkcf[i][n] = bf16_to_f(xs_rm[16 * w + 4 * g + i][16 * n + la]);

        float gsv[4][4];
#pragma unroll
        for (int i = 0; i < 4; ++i) {
            float z0 = zacc[0][i] + bcol[0], z1 = zacc[1][i] + bcol[1];
            float z2 = zacc[2][i] + bcol[2], z3 = zacc[3][i] + bcol[3];
            float mu = red16(z0 + z1 + z2 + z3) * (1.0f / DC);
            float d0 = z0 - mu, d1 = z1 - mu, d2 = z2 - mu, d3 = z3 - mu;
            float var = red16(d0 * d0 + d1 * d1 + d2 * d2 + d3 * d3) * (1.0f / DC);
            float rstd = rsqrtf(var + EPSF);
            float thd = red16(xkcf[i][0] * thv[0] + xkcf[i][1] * thv[1] +
                              xkcf[i][2] * thv[2] + xkcf[i][3] * thv[3]);
            float lr  = 1.0f / (1.0f + expf(-(thd + tb)));
            float eta = tok[i] * lr * (1.0f / DC);
            float xh[4], gxh[4], s1 = 0.f, s2 = 0.f;
            float dv[4] = {d0, d1, d2, d3};
#pragma unroll
            for (int n = 0; n < 4; ++n) {
                xh[n] = dv[n] * rstd;
                float y  = fmaf(gam[n], xh[n], bet[n]);
                float go = y - xvf[i][n] + xkcf[i][n];
                gxh[n] = go * gam[n];
                s1 += gxh[n];
                s2 = fmaf(gxh[n], xh[n], s2);
            }
            s1 = red16(s1); s2 = red16(s2);
            float sc = rstd * (1.0f / DC) * eta;
#pragma unroll
            for (int n = 0; n < 4; ++n)
                gsv[i][n] = (64.0f * gxh[n] - s1 - xh[n] * s2) * sc;
        }
        // write gs^T (A of dW) + db partials
#pragma unroll
        for (int i = 0; i < 4; ++i)
#pragma unroll
            for (int n = 0; n < 4; ++n)
                gsT[16 * n + la][16 * w + 4 * g + i] = cvt_bf16(gsv[i][n]);
        float dbl[4];
#pragma unroll
        for (int n = 0; n < 4; ++n) {
            dbl[n] = gsv[0][n] + gsv[1][n] + gsv[2][n] + gsv[3][n];
            dbl[n] += __shfl_xor(dbl[n], 16);
            dbl[n] += __shfl_xor(dbl[n], 32);
        }
        if (l < 16) {
#pragma unroll
            for (int n = 0; n < 4; ++n) dbp[w][16 * n + la] = dbl[n];
        }
        __syncthreads();

        // ---- 4. dW^T = gs^T @ xs  (wave owns rows e in [16w,16w+16)); state update in regs
        bf16x8 ag0 = *(const bf16x8*)&gsT[16 * w + la][8 * g];
        bf16x8 ag1 = *(const bf16x8*)&gsT[16 * w + la][8 * g + 32];
#pragma unroll
        for (int n = 0; n < 4; ++n) {
            bf16x8 b0 = *(const bf16x8*)&xsT[16 * n + la][8 * g];
            bf16x8 b1 = *(const bf16x8*)&xsT[16 * n + la][8 * g + 32];
            f32x4 dw = {0.f, 0.f, 0.f, 0.f};
            dw = __builtin_amdgcn_mfma_f32_16x16x32_bf16(ag0, b0, dw, 0, 0, 0);
            dw = __builtin_amdgcn_mfma_f32_16x16x32_bf16(ag1, b1, dw, 0, 0, 0);
#pragma unroll
            for (int i = 0; i < 4; ++i) Wreg[i][n] -= dw[i];
        }
#pragma unroll
        for (int n = 0; n < 4; ++n)
            bcol[n] -= dbp[0][16 * n + la] + dbp[1][16 * n + la] +
                       dbp[2][16 * n + la] + dbp[3][16 * n + la];
        // re-encode W^T to bf16 LDS for out(c) / z(c+1)
#pragma unroll
        for (int i = 0; i < 4; ++i)
#pragma unroll
            for (int n = 0; n < 4; ++n)
                Wtb[16 * w + 4 * g + i][16 * n + la] = cvt_bf16(Wreg[i][n]);
        __syncthreads();

        // ---- 5. out = xs @ Wn + bn  (refresh bw frags, reuse A frags)
        float* oc = ob + c * CSC * DC;
#pragma unroll
        for (int n = 0; n < 4; ++n) {
            bw[n][0] = *(const bf16x8*)&Wtb[16 * n + la][8 * g];
            bw[n][1] = *(const bf16x8*)&Wtb[16 * n + la][8 * g + 32];
            f32x4 oa = {0.f, 0.f, 0.f, 0.f};
            oa = __builtin_amdgcn_mfma_f32_16x16x32_bf16(a0, bw[n][0], oa, 0, 0, 0);
            oa = __builtin_amdgcn_mfma_f32_16x16x32_bf16(a1, bw[n][1], oa, 0, 0, 0);
#pragma unroll
            for (int i = 0; i < 4; ++i)
                oc[(16 * w + 4 * g + i) * DC + 16 * n + la] = oa[i] + bcol[n];
        }
    }
}

extern "C" void kernel_launch(void* const* d_in, const int* in_sizes, int n_in,
                              void* d_out, int out_size, void* d_ws, size_t ws_size,
                              hipStream_t stream) {
    const float* xk         = (const float*)d_in[0];
    const float* xv         = (const float*)d_in[1];
    const float* weight     = (const float*)d_in[2];
    const float* bias       = (const float*)d_in[3];
    const float* gamma      = (const float*)d_in[4];
    const float* beta       = (const float*)d_in[5];
    const float* theta      = (const float*)d_in[6];
    const float* theta_bias = (const float*)d_in[7];
    const float* alpha      = (const float*)d_in[8];
    float* out = (float*)d_out;

    ttt_kernel<<<NB * NH, 256, 0, stream>>>(xk, xv, weight, bias, gamma, beta,
                                            theta, theta_bias, alpha, out);
}